// Round 18
// baseline (266.532 us; speedup 1.0000x reference)
//
#include <hip/hip_runtime.h>
#include <hip/hip_fp16.h>

#define N_NODES 50000
#define N_EDGES 800000
#define N_GRAPHS 256
#define NCB 196        // coarse buckets = ceil(50000/256), dst>>8
#define CHUNK 3125     // edges per block in coarse passes (256 blocks)
#define MBLK 782       // ceil(50000/64)

// ---------------------------------------------------------------------------
// hist_prep: blocks 0..255 coarse edge histogram (dst>>8); blocks 256..6733
// prep (pad XPh, bounds, wpack); blocks 6734..6766 zero SUMS+ticket.
// All parts independent & fully parallel.
// ---------------------------------------------------------------------------
__global__ __launch_bounds__(256)
void hist_prep(const int* __restrict__ ER, const float* __restrict__ X,
               const int* __restrict__ SEG, const float* __restrict__ W1,
               const float* __restrict__ W2, int* __restrict__ ghist,
               __half* __restrict__ XPh, int* __restrict__ start,
               float* __restrict__ WP, float* __restrict__ SUMS,
               int* __restrict__ ticket)
{
    int b = blockIdx.x;
    int t = threadIdx.x;
    if (b < 256) {                           // coarse histogram
        __shared__ int h[NCB];
        for (int i = t; i < NCB; i += 256) h[i] = 0;
        __syncthreads();
        int lo = b * CHUNK, hi = lo + CHUNK;
        for (int e = lo + t; e < hi; e += 256) atomicAdd(&h[ER[e] >> 8], 1);
        __syncthreads();
        for (int i = t; i < NCB; i += 256) ghist[i * 256 + b] = h[i];
        return;
    }
    int bid = b - 256;
    if (bid < 6250) {                        // pad: XPh fp16
        int idx = bid * 256 + t;
        int n = idx >> 5;
        int c = idx & 31;
        float v = (c < 30) ? X[n * 30 + c] : 0.f;
        XPh[(size_t)n * 32 + c] = __float2half(v);
    } else if (bid < 6446) {                 // bounds from sorted seg
        int n = (bid - 6250) * 256 + t;
        if (n >= N_NODES) return;
        int g = SEG[n];
        int gprev = (n == 0) ? -1 : SEG[n - 1];
        for (int gg = gprev + 1; gg <= g; ++gg) start[gg] = n;
        if (n == N_NODES - 1)
            for (int gg = g + 1; gg <= N_GRAPHS; ++gg) start[gg] = N_NODES;
    } else if (bid < 6478) {                 // wpack: 64 x 128
        int idx = (bid - 6446) * 256 + t;
        if (idx >= 64 * 128) return;
        int k = idx >> 7, c = idx & 127;
        float w = 0.f;
        if (k < 30) w = W1[k * 128 + c];
        else if (k >= 32 && k < 62) w = W2[(k - 32) * 128 + c];
        WP[idx] = w;
    } else {                                 // zero SUMS (8192) + ticket
        int idx = (bid - 6478) * 256 + t;
        if (idx < N_GRAPHS * 32) SUMS[idx] = 0.f;
        if (idx == N_GRAPHS * 32) *ticket = 0;
    }
}

// ---------------------------------------------------------------------------
// scan1: per-bucket exclusive scan of the 256 per-block counts, in place;
// bucket total -> bsum[b].
// ---------------------------------------------------------------------------
__global__ __launch_bounds__(256)
void scan1(int* __restrict__ ghist, int* __restrict__ bsum)
{
    __shared__ int s[256];
    int t = threadIdx.x, b = blockIdx.x;
    int i = b * 256 + t;
    int v = ghist[i];
    s[t] = v;
    __syncthreads();
    for (int off = 1; off < 256; off <<= 1) {
        int u = (t >= off) ? s[t - off] : 0;
        __syncthreads();
        s[t] += u;
        __syncthreads();
    }
    ghist[i] = s[t] - v;
    if (t == 255) bsum[b] = s[255];
}

// ---------------------------------------------------------------------------
// c_scatter: coarse scatter into per-block contiguous runs.
// tmp_sd = src | ((dst&255)<<16) (4B); tmp_w = fp16 weight (2B).
// ---------------------------------------------------------------------------
__global__ __launch_bounds__(256)
void c_scatter(const int* __restrict__ ER, const int* __restrict__ EC,
               const float* __restrict__ EW, const int* __restrict__ ghist,
               const int* __restrict__ bsum, unsigned int* __restrict__ tmp_sd,
               __half* __restrict__ tmp_w)
{
    __shared__ int s[256];
    __shared__ int cur[NCB];
    int t = threadIdx.x, blk = blockIdx.x;
    int v = (t < NCB) ? bsum[t] : 0;
    s[t] = v;
    __syncthreads();
    for (int off = 1; off < 256; off <<= 1) {
        int u = (t >= off) ? s[t - off] : 0;
        __syncthreads();
        s[t] += u;
        __syncthreads();
    }
    if (t < NCB) cur[t] = (s[t] - v) + ghist[t * 256 + blk];
    __syncthreads();
    int lo = blk * CHUNK, hi = lo + CHUNK;
    for (int e = lo + t; e < hi; e += 256) {
        int d = ER[e];
        int pos = atomicAdd(&cur[d >> 8], 1);
        tmp_sd[pos] = (unsigned int)EC[e] | ((unsigned int)(d & 255) << 16);
        tmp_w[pos] = __float2half(EW[e]);
    }
}

// ---------------------------------------------------------------------------
// fp16 gather helper
// ---------------------------------------------------------------------------
__device__ __forceinline__ void fma8h(float4& a0, float4& a1, float w,
                                      const uint4& raw)
{
    const __half2* hp = (const __half2*)&raw;
    float2 f0 = __half22float2(hp[0]);
    float2 f1 = __half22float2(hp[1]);
    float2 f2 = __half22float2(hp[2]);
    float2 f3 = __half22float2(hp[3]);
    a0.x = fmaf(w, f0.x, a0.x); a0.y = fmaf(w, f0.y, a0.y);
    a0.z = fmaf(w, f1.x, a0.z); a0.w = fmaf(w, f1.y, a0.w);
    a1.x = fmaf(w, f2.x, a1.x); a1.y = fmaf(w, f2.y, a1.y);
    a1.z = fmaf(w, f3.x, a1.z); a1.w = fmaf(w, f3.y, a1.w);
}

// ---------------------------------------------------------------------------
// bsort_aggx (512 thr): per-bucket counting sort -> packed + rowptr, then the
// same block does layer-1 aggx for its own 256 nodes (packed L1/L2-hot).
// ---------------------------------------------------------------------------
__global__ __launch_bounds__(512)
void bsort_aggx(const unsigned int* __restrict__ tmp_sd, const __half* __restrict__ tmp_w,
                const int* __restrict__ bsum, const __half* __restrict__ XPh,
                unsigned int* __restrict__ packed, int* __restrict__ rowptr,
                __half* __restrict__ CIa)
{
    __shared__ int s[256];
    __shared__ int hist[256];
    __shared__ int cur[256];
    __shared__ int r0arr[257];
    int t = threadIdx.x, b = blockIdx.x;

    if (t < 256) s[t] = (t < NCB) ? bsum[t] : 0;
    __syncthreads();
    for (int off = 1; off < 256; off <<= 1) {
        int u = 0;
        if (t < 256 && t >= off) u = s[t - off];
        __syncthreads();
        if (t < 256) s[t] += u;
        __syncthreads();
    }
    int cntb = bsum[b];
    int base = s[b] - cntb;
    int end  = base + cntb;
    __syncthreads();

    if (t < 256) hist[t] = 0;
    __syncthreads();
    for (int j = base + t; j < end; j += 512)
        atomicAdd(&hist[(tmp_sd[j] >> 16) & 255], 1);
    __syncthreads();
    int hv = 0;
    if (t < 256) { hv = hist[t]; s[t] = hv; }
    __syncthreads();
    for (int off = 1; off < 256; off <<= 1) {
        int u = 0;
        if (t < 256 && t >= off) u = s[t - off];
        __syncthreads();
        if (t < 256) s[t] += u;
        __syncthreads();
    }
    if (t < 256) {
        int excl = s[t] - hv;
        int n = b * 256 + t;
        if (n < N_NODES) rowptr[n] = base + excl;
        if (b == NCB - 1 && t == 0) rowptr[N_NODES] = N_EDGES;
        r0arr[t] = base + excl;
        cur[t] = base + excl;
        if (t == 0) r0arr[256] = end;
    }
    __syncthreads();
    for (int j = base + t; j < end; j += 512) {
        unsigned int sd = tmp_sd[j];
        unsigned short hb = __half_as_ushort(tmp_w[j]);
        int pos = atomicAdd(&cur[(sd >> 16) & 255], 1);
        packed[pos] = (sd & 0xFFFF) | ((unsigned int)hb << 16);
    }
    __syncthreads();   // packed writes drained

    // aggx: 4 lanes/node, 128 nodes/pass, 2 passes; unroll-4 gather.
    #pragma unroll
    for (int pass = 0; pass < 2; ++pass) {
        int local = pass * 128 + (t >> 2);
        int q = t & 3;
        int n = b * 256 + local;
        if (n < N_NODES) {
            int r0 = r0arr[local], r1 = r0arr[local + 1];
            float4 acc0 = make_float4(0.f, 0.f, 0.f, 0.f);
            float4 acc1 = make_float4(0.f, 0.f, 0.f, 0.f);
            int j = r0;
            for (; j + 3 < r1; j += 4) {
                unsigned int ra = packed[j],     rb = packed[j + 1];
                unsigned int rc = packed[j + 2], rd = packed[j + 3];
                uint4 rawa = *(const uint4*)(XPh + (size_t)(ra & 0xFFFF) * 32 + q * 8);
                uint4 rawb = *(const uint4*)(XPh + (size_t)(rb & 0xFFFF) * 32 + q * 8);
                uint4 rawc = *(const uint4*)(XPh + (size_t)(rc & 0xFFFF) * 32 + q * 8);
                uint4 rawd = *(const uint4*)(XPh + (size_t)(rd & 0xFFFF) * 32 + q * 8);
                float wa = __half2float(__ushort_as_half((unsigned short)(ra >> 16)));
                float wb = __half2float(__ushort_as_half((unsigned short)(rb >> 16)));
                float wc = __half2float(__ushort_as_half((unsigned short)(rc >> 16)));
                float wd = __half2float(__ushort_as_half((unsigned short)(rd >> 16)));
                fma8h(acc0, acc1, wa, rawa);
                fma8h(acc0, acc1, wb, rawb);
                fma8h(acc0, acc1, wc, rawc);
                fma8h(acc0, acc1, wd, rawd);
            }
            for (; j < r1; ++j) {
                unsigned int r = packed[j];
                uint4 raw = *(const uint4*)(XPh + (size_t)(r & 0xFFFF) * 32 + q * 8);
                float w = __half2float(__ushort_as_half((unsigned short)(r >> 16)));
                fma8h(acc0, acc1, w, raw);
            }
            __half2 hb2[4];
            hb2[0] = __float22half2_rn(make_float2(acc0.x, acc0.y));
            hb2[1] = __float22half2_rn(make_float2(acc0.z, acc0.w));
            hb2[2] = __float22half2_rn(make_float2(acc1.x, acc1.y));
            hb2[3] = __float22half2_rn(make_float2(acc1.z, acc1.w));
            *(uint4*)(CIa + (size_t)n * 32 + q * 8) = *(uint4*)&hb2[0];
        }
    }
}

// ---------------------------------------------------------------------------
// Dense GEMM core: lane = row, wave owns 16 cols, B via scalar path.
// ---------------------------------------------------------------------------
template<int K>
__device__ __forceinline__ void gemm16(const float* arow,
                                       const float* __restrict__ Wcol,
                                       int wstride, float acc[16])
{
    #pragma unroll
    for (int j = 0; j < 16; ++j) acc[j] = 0.f;
    for (int k = 0; k < K; k += 4) {
        float4 a = *(const float4*)(arow + k);
        float av[4] = {a.x, a.y, a.z, a.w};
        #pragma unroll
        for (int kk = 0; kk < 4; ++kk) {
            const float* wr = Wcol + (k + kk) * wstride;   // uniform address
            #pragma unroll
            for (int j = 0; j < 16; ++j)
                acc[j] = fmaf(av[kk], wr[j], acc[j]);
        }
    }
}

__device__ __forceinline__ void addbias16(float acc[16],
                                          const float* __restrict__ Bcol)
{
    #pragma unroll
    for (int j4 = 0; j4 < 4; ++j4) {
        float4 bb = *(const float4*)(Bcol + j4 * 4);
        acc[j4*4+0] += bb.x; acc[j4*4+1] += bb.y;
        acc[j4*4+2] += bb.z; acc[j4*4+3] += bb.w;
    }
}

__device__ __forceinline__ void store16h(__half* orow, const float acc[16])
{
    __half2 hb[8];
    #pragma unroll
    for (int j = 0; j < 8; ++j)
        hb[j] = __float22half2_rn(make_float2(acc[2*j], acc[2*j+1]));
    *(uint4*)(orow)     = *(uint4*)&hb[0];
    *(uint4*)(orow + 8) = *(uint4*)&hb[4];
}

// fp16 input staging into fp32 LDS tile (stride K+4), optional relu.
template<int K, int TPB, bool RELU>
__device__ __forceinline__ void stage_Ah(const __half* __restrict__ X,
                                         float* As, int m0)
{
    constexpr int KP = K + 4;
    for (int i = threadIdx.x * 4; i < 64 * K; i += TPB * 4) {
        int row = i / K;
        int col = i % K;
        int gm = m0 + row;
        float4 v = make_float4(0.f, 0.f, 0.f, 0.f);
        if (gm < N_NODES) {
            uint2 raw = *(const uint2*)(X + (size_t)gm * K + col);
            const __half2* hp = (const __half2*)&raw;
            float2 f0 = __half22float2(hp[0]);
            float2 f1 = __half22float2(hp[1]);
            v = make_float4(f0.x, f0.y, f1.x, f1.y);
        }
        if (RELU) {
            v.x = fmaxf(v.x, 0.f); v.y = fmaxf(v.y, 0.f);
            v.z = fmaxf(v.z, 0.f); v.w = fmaxf(v.w, 0.f);
        }
        *(float4*)(As + row * KP + col) = v;
    }
    __syncthreads();
}

// ---------------------------------------------------------------------------
// dense12: FUSED layers 1+2. Phase A: [CIa|XPh] @ WP + b1 -> h1 (fp32 regs).
// Phase B: relu(h1) via LDS -> @ [W1_2|W2_2] -> H2h / A2h (+b2).
// ---------------------------------------------------------------------------
__global__ __launch_bounds__(512)
void dense12_kernel(const __half* __restrict__ CIa, const __half* __restrict__ XPh,
                    const float* __restrict__ WP, const float* __restrict__ B1,
                    const float* __restrict__ W1_2, const float* __restrict__ W2_2,
                    const float* __restrict__ B2, __half* __restrict__ H2h,
                    __half* __restrict__ A2h)
{
    __shared__ float As[64 * 132];
    const int tid = threadIdx.x;
    const int m0 = blockIdx.x * 64;

    for (int i = tid * 4; i < 64 * 64; i += 512 * 4) {
        int row = i >> 6, col = i & 63;
        int gm = m0 + row;
        float4 v = make_float4(0.f, 0.f, 0.f, 0.f);
        if (gm < N_NODES) {
            const __half* src = (col < 32) ? (CIa + (size_t)gm * 32 + col)
                                           : (XPh + (size_t)gm * 32 + (col - 32));
            uint2 raw = *(const uint2*)src;
            const __half2* hp = (const __half2*)&raw;
            float2 f0 = __half22float2(hp[0]);
            float2 f1 = __half22float2(hp[1]);
            v = make_float4(f0.x, f0.y, f1.x, f1.y);
        }
        *(float4*)(As + row * 68 + col) = v;
    }
    __syncthreads();

    const int wid = __builtin_amdgcn_readfirstlane(tid >> 6);
    const int lane = tid & 63;

    float acc[16];
    gemm16<64>(As + lane * 68, WP + wid * 16, 128, acc);
    addbias16(acc, B1 + wid * 16);
    #pragma unroll
    for (int j = 0; j < 16; ++j) acc[j] = fmaxf(acc[j], 0.f);

    __syncthreads();
    #pragma unroll
    for (int j4 = 0; j4 < 4; ++j4)
        *(float4*)(As + lane * 132 + wid * 16 + j4 * 4) =
            make_float4(acc[j4*4+0], acc[j4*4+1], acc[j4*4+2], acc[j4*4+3]);
    __syncthreads();

    const float* Wc = (wid < 4) ? (W1_2 + wid * 16) : (W2_2 + (wid - 4) * 16);
    float acc2[16];
    gemm16<128>(As + lane * 132, Wc, 64, acc2);
    int gm = m0 + lane;
    if (gm < N_NODES) {
        if (wid < 4)
            store16h(H2h + (size_t)gm * 64 + wid * 16, acc2);
        else {
            addbias16(acc2, B2 + (wid - 4) * 16);
            store16h(A2h + (size_t)gm * 64 + (wid - 4) * 16, acc2);
        }
    }
}

// Layer 3: relu(h2h) (N x 64 fp16); waves 0-1 -> W1 -> H3h, 2-3 -> W2 -> B2h (+b).
__global__ __launch_bounds__(256)
void dense3_kernel(const __half* __restrict__ X, const float* __restrict__ W1,
                   const float* __restrict__ W2, const float* __restrict__ Bias,
                   __half* __restrict__ HW1h, __half* __restrict__ AGGh)
{
    __shared__ float As[64 * 68];
    const int m0 = blockIdx.x * 64;
    stage_Ah<64, 256, true>(X, As, m0);
    int wid = __builtin_amdgcn_readfirstlane(threadIdx.x >> 6);
    int lane = threadIdx.x & 63;
    const float* Wc = (wid < 2) ? (W1 + wid * 16) : (W2 + (wid - 2) * 16);
    float acc[16];
    gemm16<64>(As + lane * 68, Wc, 32, acc);
    int gm = m0 + lane;
    if (gm < N_NODES) {
        if (wid < 2)
            store16h(HW1h + (size_t)gm * 32 + wid * 16, acc);
        else {
            addbias16(acc, Bias + (wid - 2) * 16);
            store16h(AGGh + (size_t)gm * 32 + (wid - 2) * 16, acc);
        }
    }
}

// ---------------------------------------------------------------------------
// spmm_h<64>: fp16 gather rows, fp32 accumulate on top of fp16 AGG (RMW).
// ---------------------------------------------------------------------------
template<int FOUT>
__global__ __launch_bounds__(256)
void spmm_h(const __half* __restrict__ H, const int* __restrict__ rowptr,
            const unsigned int* __restrict__ packed, __half* __restrict__ AGGh)
{
    constexpr int T = FOUT / 8;
    int tid = threadIdx.x;
    int local = tid / T;
    int q = tid % T;
    int n = blockIdx.x * (256 / T) + local;
    if (n >= N_NODES) return;
    int r0 = rowptr[n], r1 = rowptr[n + 1];
    __half* ap = AGGh + (size_t)n * FOUT + q * 8;
    float4 acc0, acc1;
    {
        uint4 raw = *(const uint4*)ap;
        const __half2* hp = (const __half2*)&raw;
        float2 f0 = __half22float2(hp[0]);
        float2 f1 = __half22float2(hp[1]);
        float2 f2 = __half22float2(hp[2]);
        float2 f3 = __half22float2(hp[3]);
        acc0 = make_float4(f0.x, f0.y, f1.x, f1.y);
        acc1 = make_float4(f2.x, f2.y, f3.x, f3.y);
    }
    int j = r0;
    for (; j + 3 < r1; j += 4) {
        unsigned int ra = packed[j],     rb = packed[j + 1];
        unsigned int rc = packed[j + 2], rd = packed[j + 3];
        uint4 rawa = *(const uint4*)(H + (size_t)(ra & 0xFFFF) * FOUT + q * 8);
        uint4 rawb = *(const uint4*)(H + (size_t)(rb & 0xFFFF) * FOUT + q * 8);
        uint4 rawc = *(const uint4*)(H + (size_t)(rc & 0xFFFF) * FOUT + q * 8);
        uint4 rawd = *(const uint4*)(H + (size_t)(rd & 0xFFFF) * FOUT + q * 8);
        float wa = __half2float(__ushort_as_half((unsigned short)(ra >> 16)));
        float wb = __half2float(__ushort_as_half((unsigned short)(rb >> 16)));
        float wc = __half2float(__ushort_as_half((unsigned short)(rc >> 16)));
        float wd = __half2float(__ushort_as_half((unsigned short)(rd >> 16)));
        fma8h(acc0, acc1, wa, rawa);
        fma8h(acc0, acc1, wb, rawb);
        fma8h(acc0, acc1, wc, rawc);
        fma8h(acc0, acc1, wd, rawd);
    }
    for (; j < r1; ++j) {
        unsigned int r = packed[j];
        uint4 raw = *(const uint4*)(H + (size_t)(r & 0xFFFF) * FOUT + q * 8);
        float w = __half2float(__ushort_as_half((unsigned short)(r >> 16)));
        fma8h(acc0, acc1, w, raw);
    }
    __half2 hb[4];
    hb[0] = __float22half2_rn(make_float2(acc0.x, acc0.y));
    hb[1] = __float22half2_rn(make_float2(acc0.z, acc0.w));
    hb[2] = __float22half2_rn(make_float2(acc1.x, acc1.y));
    hb[3] = __float22half2_rn(make_float2(acc1.z, acc1.w));
    *(uint4*)ap = *(uint4*)&hb[0];
}

// ---------------------------------------------------------------------------
// spmm32_pool: layer-3 SpMM (h3 = B2h-init + gather, NEVER materialized) +
// relu + per-graph pooling. Block = 64 sorted nodes -> LDS bins (up to 128
// graphs; overflow -> direct global atomics), flush nonzero bins to SUMS via
// device atomics, ticket elects last block to run the softmax head.
// ---------------------------------------------------------------------------
__global__ __launch_bounds__(256)
void spmm32_pool(const __half* __restrict__ H, const int* __restrict__ rowptr,
                 const unsigned int* __restrict__ packed,
                 const __half* __restrict__ AGGh, const int* __restrict__ SEG,
                 const int* __restrict__ start, const float* __restrict__ WD,
                 const float* __restrict__ BD, float* __restrict__ SUMS,
                 int* __restrict__ ticket, float* __restrict__ OUT)
{
    __shared__ float bins[128 * 32];
    __shared__ int sflag;
    __shared__ int sgfirst;
    const int tid = threadIdx.x;
    const int local = tid >> 2;          // 64 nodes/block
    const int q = tid & 3;               // 8 features each
    const int n = blockIdx.x * 64 + local;

    for (int i = tid; i < 128 * 32; i += 256) bins[i] = 0.f;
    if (tid == 0) sgfirst = SEG[blockIdx.x * 64];
    __syncthreads();
    const int gfirst = sgfirst;

    if (n < N_NODES) {
        int r0 = rowptr[n], r1 = rowptr[n + 1];
        const __half* ap = AGGh + (size_t)n * 32 + q * 8;
        float4 acc0, acc1;
        {
            uint4 raw = *(const uint4*)ap;
            const __half2* hp = (const __half2*)&raw;
            float2 f0 = __half22float2(hp[0]);
            float2 f1 = __half22float2(hp[1]);
            float2 f2 = __half22float2(hp[2]);
            float2 f3 = __half22float2(hp[3]);
            acc0 = make_float4(f0.x, f0.y, f1.x, f1.y);
            acc1 = make_float4(f2.x, f2.y, f3.x, f3.y);
        }
        int j = r0;
        for (; j + 3 < r1; j += 4) {
            unsigned int ra = packed[j],     rb = packed[j + 1];
            unsigned int rc = packed[j + 2], rd = packed[j + 3];
            uint4 rawa = *(const uint4*)(H + (size_t)(ra & 0xFFFF) * 32 + q * 8);
            uint4 rawb = *(const uint4*)(H + (size_t)(rb & 0xFFFF) * 32 + q * 8);
            uint4 rawc = *(const uint4*)(H + (size_t)(rc & 0xFFFF) * 32 + q * 8);
            uint4 rawd = *(const uint4*)(H + (size_t)(rd & 0xFFFF) * 32 + q * 8);
            float wa = __half2float(__ushort_as_half((unsigned short)(ra >> 16)));
            float wb = __half2float(__ushort_as_half((unsigned short)(rb >> 16)));
            float wc = __half2float(__ushort_as_half((unsigned short)(rc >> 16)));
            float wd = __half2float(__ushort_as_half((unsigned short)(rd >> 16)));
            fma8h(acc0, acc1, wa, rawa);
            fma8h(acc0, acc1, wb, rawb);
            fma8h(acc0, acc1, wc, rawc);
            fma8h(acc0, acc1, wd, rawd);
        }
        for (; j < r1; ++j) {
            unsigned int r = packed[j];
            uint4 raw = *(const uint4*)(H + (size_t)(r & 0xFFFF) * 32 + q * 8);
            float w = __half2float(__ushort_as_half((unsigned short)(r >> 16)));
            fma8h(acc0, acc1, w, raw);
        }
        // relu + accumulate into per-graph bins
        float v[8] = {fmaxf(acc0.x,0.f), fmaxf(acc0.y,0.f), fmaxf(acc0.z,0.f),
                      fmaxf(acc0.w,0.f), fmaxf(acc1.x,0.f), fmaxf(acc1.y,0.f),
                      fmaxf(acc1.z,0.f), fmaxf(acc1.w,0.f)};
        int g = SEG[n];
        int gl = g - gfirst;
        if (gl < 128) {
            #pragma unroll
            for (int i = 0; i < 8; ++i)
                atomicAdd(&bins[gl * 32 + q * 8 + i], v[i]);
        } else {
            #pragma unroll
            for (int i = 0; i < 8; ++i)
                atomicAdd(&SUMS[g * 32 + q * 8 + i], v[i]);
        }
    }
    __syncthreads();

    // flush nonzero bins to global SUMS
    for (int i = tid; i < 128 * 32; i += 256) {
        float bv = bins[i];
        if (bv != 0.f) {
            int gg = gfirst + (i >> 5);
            if (gg < N_GRAPHS) atomicAdd(&SUMS[gg * 32 + (i & 31)], bv);
        }
    }
    __threadfence();
    if (tid == 0) {
        int old = atomicAdd(ticket, 1);
        sflag = (old == (int)gridDim.x - 1) ? 1 : 0;
    }
    __syncthreads();
    if (!sflag) return;

    // HEAD (last block): thread t handles graph t
    if (tid < N_GRAPHS) {
        int g = tid;
        int cnt = start[g + 1] - start[g];
        float inv = 1.0f / fmaxf((float)cnt, 1.0f);
        float l0 = BD[0], l1 = BD[1];
        #pragma unroll 4
        for (int k = 0; k < 32; ++k) {
            float sv = atomicAdd(&SUMS[g * 32 + k], 0.0f);  // coherent read
            float p = sv * inv;
            l0 = fmaf(p, WD[k * 2 + 0], l0);
            l1 = fmaf(p, WD[k * 2 + 1], l1);
        }
        float m = fmaxf(l0, l1);
        float e0 = expf(l0 - m), e1 = expf(l1 - m);
        float si = 1.0f / (e0 + e1);
        OUT[g * 2 + 0] = e0 * si;
        OUT[g * 2 + 1] = e1 * si;
    }
}

extern "C" void kernel_launch(void* const* d_in, const int* in_sizes, int n_in,
                              void* d_out, int out_size, void* d_ws, size_t ws_size,
                              hipStream_t stream)
{
    const float* x    = (const float*)d_in[0];
    const float* ew   = (const float*)d_in[1];
    const int*   er   = (const int*)d_in[2];
    const int*   ec   = (const int*)d_in[3];
    const int*   seg  = (const int*)d_in[4];
    const float* w1_1 = (const float*)d_in[5];
    const float* w2_1 = (const float*)d_in[6];
    const float* b_1  = (const float*)d_in[7];
    const float* w1_2 = (const float*)d_in[8];
    const float* w2_2 = (const float*)d_in[9];
    const float* b_2  = (const float*)d_in[10];
    const float* w1_3 = (const float*)d_in[11];
    const float* w2_3 = (const float*)d_in[12];
    const float* b_3  = (const float*)d_in[13];
    const float* wd   = (const float*)d_in[14];
    const float* bd   = (const float*)d_in[15];

    float* ws = (float*)d_ws;
    int*   IW = (int*)d_ws;
    // Fully disjoint workspace — no aliasing hazards.
    __half* XPh    = (__half*)ws;                   // N x 32 fp16
    __half* CIa    = (__half*)(ws + 800000);        // N x 32 fp16
    unsigned int* tmp_sd = (unsigned int*)(ws + 1600000);  // E x 4B
    __half* tmp_w  = (__half*)(ws + 2400000);       // E x 2B
    __half* H2h    = (__half*)(ws + 3200000);       // N x 64 fp16
    __half* A2h    = (__half*)(ws + 4800000);       // N x 64 fp16
    __half* H3h    = (__half*)(ws + 6400000);       // N x 32 fp16
    __half* B2h    = (__half*)(ws + 7200000);       // N x 32 fp16 (agg3 init)
    unsigned int* packed = (unsigned int*)(IW + 8000000);  // E x 4B
    int*    rowptr = IW + 9000000;                  // N+1
    int*    ghist  = IW + 9060000;                  // NCB*256
    int*    bsum   = IW + 9115000;                  // NCB
    int*    start  = IW + 9120000;                  // G+1
    float*  WP     = ws + 9125000;                  // 64 x 128 packed layer-1 W
    float*  SUMS   = ws + 9135000;                  // 256 x 32
    int*    ticket = IW + 9145000;                  // 1

    dim3 blk(256);

    // ---- CSR build + prep (bsort fuses layer-1 aggx; prep zeros SUMS/ticket) ----
    hist_prep<<<dim3(256 + 6478 + 33), blk, 0, stream>>>(er, x, seg, w1_1, w2_1,
                                                         ghist, XPh, start, WP,
                                                         SUMS, ticket);
    scan1<<<dim3(NCB), blk, 0, stream>>>(ghist, bsum);
    c_scatter<<<dim3(256), blk, 0, stream>>>(er, ec, ew, ghist, bsum, tmp_sd, tmp_w);
    bsort_aggx<<<dim3(NCB), dim3(512), 0, stream>>>(tmp_sd, tmp_w, bsum, XPh,
                                                    packed, rowptr, CIa);

    // Layers 1+2 fused dense: [CIa|XPh] @ WP + b1 -> relu -> @[W1_2|W2_2]
    dense12_kernel<<<dim3(MBLK), dim3(512), 0, stream>>>(CIa, XPh, WP, b_1,
                                                         w1_2, w2_2, b_2, H2h, A2h);
    spmm_h<64><<<dim3((N_NODES + 31) / 32), blk, 0, stream>>>(H2h, rowptr, packed, A2h);
    // Layer 3 dense: relu(h2h)(64) -> 32
    dense3_kernel<<<dim3(MBLK), blk, 0, stream>>>(A2h, w1_3, w2_3, b_3, H3h, B2h);
    // Layer-3 SpMM + pool + head, fused (h3 never materialized)
    spmm32_pool<<<dim3(MBLK), blk, 0, stream>>>(H3h, rowptr, packed, B2h, seg,
                                                start, wd, bd, SUMS, ticket,
                                                (float*)d_out);
}

// Round 19
// 213.336 us; speedup vs baseline: 1.2493x; 1.2493x over previous
//
#include <hip/hip_runtime.h>
#include <hip/hip_fp16.h>

#define N_NODES 50000
#define N_EDGES 800000
#define N_GRAPHS 256
#define NCB 196        // coarse buckets = ceil(50000/256), dst>>8
#define CHUNK 3125     // edges per block in coarse passes (256 blocks)
#define MBLK 782       // ceil(50000/64)

// ---------------------------------------------------------------------------
// hist_prep: blocks 0..255 coarse edge histogram (dst>>8); blocks 256..6733
// independent prep (pad XPh, bounds, wpack). Merged: both fully parallel.
// ---------------------------------------------------------------------------
__global__ __launch_bounds__(256)
void hist_prep(const int* __restrict__ ER, const float* __restrict__ X,
               const int* __restrict__ SEG, const float* __restrict__ W1,
               const float* __restrict__ W2, int* __restrict__ ghist,
               __half* __restrict__ XPh, int* __restrict__ start,
               float* __restrict__ WP)
{
    int b = blockIdx.x;
    int t = threadIdx.x;
    if (b < 256) {                           // coarse histogram
        __shared__ int h[NCB];
        for (int i = t; i < NCB; i += 256) h[i] = 0;
        __syncthreads();
        int lo = b * CHUNK, hi = lo + CHUNK;
        for (int e = lo + t; e < hi; e += 256) atomicAdd(&h[ER[e] >> 8], 1);
        __syncthreads();
        for (int i = t; i < NCB; i += 256) ghist[i * 256 + b] = h[i];
        return;
    }
    int bid = b - 256;
    if (bid < 6250) {                        // pad: XPh fp16 (dense12 X-half)
        int idx = bid * 256 + t;
        int n = idx >> 5;
        int c = idx & 31;
        float v = (c < 30) ? X[n * 30 + c] : 0.f;
        XPh[(size_t)n * 32 + c] = __float2half(v);
    } else if (bid < 6446) {                 // bounds from sorted seg
        int n = (bid - 6250) * 256 + t;
        if (n >= N_NODES) return;
        int g = SEG[n];
        int gprev = (n == 0) ? -1 : SEG[n - 1];
        for (int gg = gprev + 1; gg <= g; ++gg) start[gg] = n;
        if (n == N_NODES - 1)
            for (int gg = g + 1; gg <= N_GRAPHS; ++gg) start[gg] = N_NODES;
    } else {                                 // wpack: 64 x 128
        int idx = (bid - 6446) * 256 + t;
        if (idx >= 64 * 128) return;
        int k = idx >> 7, c = idx & 127;
        float w = 0.f;
        if (k < 30) w = W1[k * 128 + c];
        else if (k >= 32 && k < 62) w = W2[(k - 32) * 128 + c];
        WP[idx] = w;
    }
}

// ---------------------------------------------------------------------------
// scan1: per-bucket exclusive scan of the 256 per-block counts, in place;
// bucket total -> bsum[b].
// ---------------------------------------------------------------------------
__global__ __launch_bounds__(256)
void scan1(int* __restrict__ ghist, int* __restrict__ bsum)
{
    __shared__ int s[256];
    int t = threadIdx.x, b = blockIdx.x;
    int i = b * 256 + t;
    int v = ghist[i];
    s[t] = v;
    __syncthreads();
    for (int off = 1; off < 256; off <<= 1) {
        int u = (t >= off) ? s[t - off] : 0;
        __syncthreads();
        s[t] += u;
        __syncthreads();
    }
    ghist[i] = s[t] - v;
    if (t == 255) bsum[b] = s[255];
}

// ---------------------------------------------------------------------------
// c_scatter: coarse scatter into per-block contiguous runs.
// tmp_sd = src | ((dst&255)<<16) (4B); tmp_w = fp16 weight (2B).
// ---------------------------------------------------------------------------
__global__ __launch_bounds__(256)
void c_scatter(const int* __restrict__ ER, const int* __restrict__ EC,
               const float* __restrict__ EW, const int* __restrict__ ghist,
               const int* __restrict__ bsum, unsigned int* __restrict__ tmp_sd,
               __half* __restrict__ tmp_w)
{
    __shared__ int s[256];
    __shared__ int cur[NCB];
    int t = threadIdx.x, blk = blockIdx.x;
    int v = (t < NCB) ? bsum[t] : 0;
    s[t] = v;
    __syncthreads();
    for (int off = 1; off < 256; off <<= 1) {
        int u = (t >= off) ? s[t - off] : 0;
        __syncthreads();
        s[t] += u;
        __syncthreads();
    }
    if (t < NCB) cur[t] = (s[t] - v) + ghist[t * 256 + blk];
    __syncthreads();
    int lo = blk * CHUNK, hi = lo + CHUNK;
    for (int e = lo + t; e < hi; e += 256) {
        int d = ER[e];
        int pos = atomicAdd(&cur[d >> 8], 1);
        tmp_sd[pos] = (unsigned int)EC[e] | ((unsigned int)(d & 255) << 16);
        tmp_w[pos] = __float2half(EW[e]);
    }
}

// ---------------------------------------------------------------------------
// fp16 gather helper
// ---------------------------------------------------------------------------
__device__ __forceinline__ void fma8h(float4& a0, float4& a1, float w,
                                      const uint4& raw)
{
    const __half2* hp = (const __half2*)&raw;
    float2 f0 = __half22float2(hp[0]);
    float2 f1 = __half22float2(hp[1]);
    float2 f2 = __half22float2(hp[2]);
    float2 f3 = __half22float2(hp[3]);
    a0.x = fmaf(w, f0.x, a0.x); a0.y = fmaf(w, f0.y, a0.y);
    a0.z = fmaf(w, f1.x, a0.z); a0.w = fmaf(w, f1.y, a0.w);
    a1.x = fmaf(w, f2.x, a1.x); a1.y = fmaf(w, f2.y, a1.y);
    a1.z = fmaf(w, f3.x, a1.z); a1.w = fmaf(w, f3.y, a1.w);
}

// ---------------------------------------------------------------------------
// bsort_aggx (512 thr): per-bucket counting sort -> packed + rowptr, then the
// same block does layer-1 aggx for its own 256 nodes (packed L1/L2-hot).
// ---------------------------------------------------------------------------
__global__ __launch_bounds__(512)
void bsort_aggx(const unsigned int* __restrict__ tmp_sd, const __half* __restrict__ tmp_w,
                const int* __restrict__ bsum, const __half* __restrict__ XPh,
                unsigned int* __restrict__ packed, int* __restrict__ rowptr,
                __half* __restrict__ CIa)
{
    __shared__ int s[256];
    __shared__ int hist[256];
    __shared__ int cur[256];
    __shared__ int r0arr[257];
    int t = threadIdx.x, b = blockIdx.x;

    if (t < 256) s[t] = (t < NCB) ? bsum[t] : 0;
    __syncthreads();
    for (int off = 1; off < 256; off <<= 1) {
        int u = 0;
        if (t < 256 && t >= off) u = s[t - off];
        __syncthreads();
        if (t < 256) s[t] += u;
        __syncthreads();
    }
    int cntb = bsum[b];
    int base = s[b] - cntb;
    int end  = base + cntb;
    __syncthreads();

    if (t < 256) hist[t] = 0;
    __syncthreads();
    for (int j = base + t; j < end; j += 512)
        atomicAdd(&hist[(tmp_sd[j] >> 16) & 255], 1);
    __syncthreads();
    int hv = 0;
    if (t < 256) { hv = hist[t]; s[t] = hv; }
    __syncthreads();
    for (int off = 1; off < 256; off <<= 1) {
        int u = 0;
        if (t < 256 && t >= off) u = s[t - off];
        __syncthreads();
        if (t < 256) s[t] += u;
        __syncthreads();
    }
    if (t < 256) {
        int excl = s[t] - hv;
        int n = b * 256 + t;
        if (n < N_NODES) rowptr[n] = base + excl;
        if (b == NCB - 1 && t == 0) rowptr[N_NODES] = N_EDGES;
        r0arr[t] = base + excl;
        cur[t] = base + excl;
        if (t == 0) r0arr[256] = end;
    }
    __syncthreads();
    for (int j = base + t; j < end; j += 512) {
        unsigned int sd = tmp_sd[j];
        unsigned short hb = __half_as_ushort(tmp_w[j]);
        int pos = atomicAdd(&cur[(sd >> 16) & 255], 1);
        packed[pos] = (sd & 0xFFFF) | ((unsigned int)hb << 16);
    }
    __syncthreads();   // packed writes drained

    // aggx: 4 lanes/node, 128 nodes/pass, 2 passes; unroll-4 gather.
    #pragma unroll
    for (int pass = 0; pass < 2; ++pass) {
        int local = pass * 128 + (t >> 2);
        int q = t & 3;
        int n = b * 256 + local;
        if (n < N_NODES) {
            int r0 = r0arr[local], r1 = r0arr[local + 1];
            float4 acc0 = make_float4(0.f, 0.f, 0.f, 0.f);
            float4 acc1 = make_float4(0.f, 0.f, 0.f, 0.f);
            int j = r0;
            for (; j + 3 < r1; j += 4) {
                unsigned int ra = packed[j],     rb = packed[j + 1];
                unsigned int rc = packed[j + 2], rd = packed[j + 3];
                uint4 rawa = *(const uint4*)(XPh + (size_t)(ra & 0xFFFF) * 32 + q * 8);
                uint4 rawb = *(const uint4*)(XPh + (size_t)(rb & 0xFFFF) * 32 + q * 8);
                uint4 rawc = *(const uint4*)(XPh + (size_t)(rc & 0xFFFF) * 32 + q * 8);
                uint4 rawd = *(const uint4*)(XPh + (size_t)(rd & 0xFFFF) * 32 + q * 8);
                float wa = __half2float(__ushort_as_half((unsigned short)(ra >> 16)));
                float wb = __half2float(__ushort_as_half((unsigned short)(rb >> 16)));
                float wc = __half2float(__ushort_as_half((unsigned short)(rc >> 16)));
                float wd = __half2float(__ushort_as_half((unsigned short)(rd >> 16)));
                fma8h(acc0, acc1, wa, rawa);
                fma8h(acc0, acc1, wb, rawb);
                fma8h(acc0, acc1, wc, rawc);
                fma8h(acc0, acc1, wd, rawd);
            }
            for (; j < r1; ++j) {
                unsigned int r = packed[j];
                uint4 raw = *(const uint4*)(XPh + (size_t)(r & 0xFFFF) * 32 + q * 8);
                float w = __half2float(__ushort_as_half((unsigned short)(r >> 16)));
                fma8h(acc0, acc1, w, raw);
            }
            __half2 hb2[4];
            hb2[0] = __float22half2_rn(make_float2(acc0.x, acc0.y));
            hb2[1] = __float22half2_rn(make_float2(acc0.z, acc0.w));
            hb2[2] = __float22half2_rn(make_float2(acc1.x, acc1.y));
            hb2[3] = __float22half2_rn(make_float2(acc1.z, acc1.w));
            *(uint4*)(CIa + (size_t)n * 32 + q * 8) = *(uint4*)&hb2[0];
        }
    }
}

// ---------------------------------------------------------------------------
// Dense GEMM core: lane = row, wave owns 16 cols, B via scalar path.
// ---------------------------------------------------------------------------
template<int K>
__device__ __forceinline__ void gemm16(const float* arow,
                                       const float* __restrict__ Wcol,
                                       int wstride, float acc[16])
{
    #pragma unroll
    for (int j = 0; j < 16; ++j) acc[j] = 0.f;
    for (int k = 0; k < K; k += 4) {
        float4 a = *(const float4*)(arow + k);
        float av[4] = {a.x, a.y, a.z, a.w};
        #pragma unroll
        for (int kk = 0; kk < 4; ++kk) {
            const float* wr = Wcol + (k + kk) * wstride;   // uniform address
            #pragma unroll
            for (int j = 0; j < 16; ++j)
                acc[j] = fmaf(av[kk], wr[j], acc[j]);
        }
    }
}

__device__ __forceinline__ void addbias16(float acc[16],
                                          const float* __restrict__ Bcol)
{
    #pragma unroll
    for (int j4 = 0; j4 < 4; ++j4) {
        float4 bb = *(const float4*)(Bcol + j4 * 4);
        acc[j4*4+0] += bb.x; acc[j4*4+1] += bb.y;
        acc[j4*4+2] += bb.z; acc[j4*4+3] += bb.w;
    }
}

__device__ __forceinline__ void store16h(__half* orow, const float acc[16])
{
    __half2 hb[8];
    #pragma unroll
    for (int j = 0; j < 8; ++j)
        hb[j] = __float22half2_rn(make_float2(acc[2*j], acc[2*j+1]));
    *(uint4*)(orow)     = *(uint4*)&hb[0];
    *(uint4*)(orow + 8) = *(uint4*)&hb[4];
}

// fp16 input staging into fp32 LDS tile (stride K+4), optional relu.
template<int K, int TPB, bool RELU>
__device__ __forceinline__ void stage_Ah(const __half* __restrict__ X,
                                         float* As, int m0)
{
    constexpr int KP = K + 4;
    for (int i = threadIdx.x * 4; i < 64 * K; i += TPB * 4) {
        int row = i / K;
        int col = i % K;
        int gm = m0 + row;
        float4 v = make_float4(0.f, 0.f, 0.f, 0.f);
        if (gm < N_NODES) {
            uint2 raw = *(const uint2*)(X + (size_t)gm * K + col);
            const __half2* hp = (const __half2*)&raw;
            float2 f0 = __half22float2(hp[0]);
            float2 f1 = __half22float2(hp[1]);
            v = make_float4(f0.x, f0.y, f1.x, f1.y);
        }
        if (RELU) {
            v.x = fmaxf(v.x, 0.f); v.y = fmaxf(v.y, 0.f);
            v.z = fmaxf(v.z, 0.f); v.w = fmaxf(v.w, 0.f);
        }
        *(float4*)(As + row * KP + col) = v;
    }
    __syncthreads();
}

// ---------------------------------------------------------------------------
// dense12: FUSED layers 1+2. Phase A: [CIa|XPh] @ WP + b1 -> h1 (fp32 regs).
// Phase B: relu(h1) via LDS -> @ [W1_2|W2_2] -> H2h / A2h (+b2).
// ---------------------------------------------------------------------------
__global__ __launch_bounds__(512)
void dense12_kernel(const __half* __restrict__ CIa, const __half* __restrict__ XPh,
                    const float* __restrict__ WP, const float* __restrict__ B1,
                    const float* __restrict__ W1_2, const float* __restrict__ W2_2,
                    const float* __restrict__ B2, __half* __restrict__ H2h,
                    __half* __restrict__ A2h)
{
    __shared__ float As[64 * 132];
    const int tid = threadIdx.x;
    const int m0 = blockIdx.x * 64;

    for (int i = tid * 4; i < 64 * 64; i += 512 * 4) {
        int row = i >> 6, col = i & 63;
        int gm = m0 + row;
        float4 v = make_float4(0.f, 0.f, 0.f, 0.f);
        if (gm < N_NODES) {
            const __half* src = (col < 32) ? (CIa + (size_t)gm * 32 + col)
                                           : (XPh + (size_t)gm * 32 + (col - 32));
            uint2 raw = *(const uint2*)src;
            const __half2* hp = (const __half2*)&raw;
            float2 f0 = __half22float2(hp[0]);
            float2 f1 = __half22float2(hp[1]);
            v = make_float4(f0.x, f0.y, f1.x, f1.y);
        }
        *(float4*)(As + row * 68 + col) = v;
    }
    __syncthreads();

    const int wid = __builtin_amdgcn_readfirstlane(tid >> 6);
    const int lane = tid & 63;

    float acc[16];
    gemm16<64>(As + lane * 68, WP + wid * 16, 128, acc);
    addbias16(acc, B1 + wid * 16);
    #pragma unroll
    for (int j = 0; j < 16; ++j) acc[j] = fmaxf(acc[j], 0.f);

    __syncthreads();
    #pragma unroll
    for (int j4 = 0; j4 < 4; ++j4)
        *(float4*)(As + lane * 132 + wid * 16 + j4 * 4) =
            make_float4(acc[j4*4+0], acc[j4*4+1], acc[j4*4+2], acc[j4*4+3]);
    __syncthreads();

    const float* Wc = (wid < 4) ? (W1_2 + wid * 16) : (W2_2 + (wid - 4) * 16);
    float acc2[16];
    gemm16<128>(As + lane * 132, Wc, 64, acc2);
    int gm = m0 + lane;
    if (gm < N_NODES) {
        if (wid < 4)
            store16h(H2h + (size_t)gm * 64 + wid * 16, acc2);
        else {
            addbias16(acc2, B2 + (wid - 4) * 16);
            store16h(A2h + (size_t)gm * 64 + (wid - 4) * 16, acc2);
        }
    }
}

// Layer 3: relu(h2h) (N x 64 fp16); waves 0-1 -> W1 -> H3h, 2-3 -> W2 -> B2h (+b).
__global__ __launch_bounds__(256)
void dense3_kernel(const __half* __restrict__ X, const float* __restrict__ W1,
                   const float* __restrict__ W2, const float* __restrict__ Bias,
                   __half* __restrict__ HW1h, __half* __restrict__ AGGh)
{
    __shared__ float As[64 * 68];
    const int m0 = blockIdx.x * 64;
    stage_Ah<64, 256, true>(X, As, m0);
    int wid = __builtin_amdgcn_readfirstlane(threadIdx.x >> 6);
    int lane = threadIdx.x & 63;
    const float* Wc = (wid < 2) ? (W1 + wid * 16) : (W2 + (wid - 2) * 16);
    float acc[16];
    gemm16<64>(As + lane * 68, Wc, 32, acc);
    int gm = m0 + lane;
    if (gm < N_NODES) {
        if (wid < 2)
            store16h(HW1h + (size_t)gm * 32 + wid * 16, acc);
        else {
            addbias16(acc, Bias + (wid - 2) * 16);
            store16h(AGGh + (size_t)gm * 32 + (wid - 2) * 16, acc);
        }
    }
}

// ---------------------------------------------------------------------------
// spmm_h: fp16 gather rows, fp32 accumulate on top of fp16 AGG (RMW).
// Unrolled by 4: 4 independent 16B loads in flight per lane.
// ---------------------------------------------------------------------------
template<int FOUT>
__global__ __launch_bounds__(256)
void spmm_h(const __half* __restrict__ H, const int* __restrict__ rowptr,
            const unsigned int* __restrict__ packed, __half* __restrict__ AGGh)
{
    constexpr int T = FOUT / 8;
    int tid = threadIdx.x;
    int local = tid / T;
    int q = tid % T;
    int n = blockIdx.x * (256 / T) + local;
    if (n >= N_NODES) return;
    int r0 = rowptr[n], r1 = rowptr[n + 1];
    __half* ap = AGGh + (size_t)n * FOUT + q * 8;
    float4 acc0, acc1;
    {
        uint4 raw = *(const uint4*)ap;
        const __half2* hp = (const __half2*)&raw;
        float2 f0 = __half22float2(hp[0]);
        float2 f1 = __half22float2(hp[1]);
        float2 f2 = __half22float2(hp[2]);
        float2 f3 = __half22float2(hp[3]);
        acc0 = make_float4(f0.x, f0.y, f1.x, f1.y);
        acc1 = make_float4(f2.x, f2.y, f3.x, f3.y);
    }
    int j = r0;
    for (; j + 3 < r1; j += 4) {
        unsigned int ra = packed[j],     rb = packed[j + 1];
        unsigned int rc = packed[j + 2], rd = packed[j + 3];
        uint4 rawa = *(const uint4*)(H + (size_t)(ra & 0xFFFF) * FOUT + q * 8);
        uint4 rawb = *(const uint4*)(H + (size_t)(rb & 0xFFFF) * FOUT + q * 8);
        uint4 rawc = *(const uint4*)(H + (size_t)(rc & 0xFFFF) * FOUT + q * 8);
        uint4 rawd = *(const uint4*)(H + (size_t)(rd & 0xFFFF) * FOUT + q * 8);
        float wa = __half2float(__ushort_as_half((unsigned short)(ra >> 16)));
        float wb = __half2float(__ushort_as_half((unsigned short)(rb >> 16)));
        float wc = __half2float(__ushort_as_half((unsigned short)(rc >> 16)));
        float wd = __half2float(__ushort_as_half((unsigned short)(rd >> 16)));
        fma8h(acc0, acc1, wa, rawa);
        fma8h(acc0, acc1, wb, rawb);
        fma8h(acc0, acc1, wc, rawc);
        fma8h(acc0, acc1, wd, rawd);
    }
    for (; j < r1; ++j) {
        unsigned int r = packed[j];
        uint4 raw = *(const uint4*)(H + (size_t)(r & 0xFFFF) * FOUT + q * 8);
        float w = __half2float(__ushort_as_half((unsigned short)(r >> 16)));
        fma8h(acc0, acc1, w, raw);
    }
    __half2 hb[4];
    hb[0] = __float22half2_rn(make_float2(acc0.x, acc0.y));
    hb[1] = __float22half2_rn(make_float2(acc0.z, acc0.w));
    hb[2] = __float22half2_rn(make_float2(acc1.x, acc1.y));
    hb[3] = __float22half2_rn(make_float2(acc1.z, acc1.w));
    *(uint4*)ap = *(uint4*)&hb[0];
}

// ---------------------------------------------------------------------------
// pool + head fused: one block/graph; mean of relu(h3h fp16), softmax(p@wd+bd).
// ---------------------------------------------------------------------------
__global__ __launch_bounds__(256)
void pool_kernel(const __half* __restrict__ H, const int* __restrict__ start,
                 const float* __restrict__ WD, const float* __restrict__ BD,
                 float* __restrict__ OUT)
{
    __shared__ float red[8][33];
    int g = blockIdx.x;
    int s = start[g], e = start[g + 1];
    int q = threadIdx.x & 31;
    int lane = threadIdx.x >> 5;
    float acc = 0.f;
    for (int n = s + lane; n < e; n += 8)
        acc += fmaxf(__half2float(H[(size_t)n * 32 + q]), 0.f);
    red[lane][q] = acc;
    __syncthreads();
    if (threadIdx.x < 32) {
        float v = 0.f;
        #pragma unroll
        for (int i = 0; i < 8; ++i) v += red[i][q];
        float inv = (e > s) ? 1.0f / (float)(e - s) : 1.0f;
        float p = v * inv;
        float p0 = p * WD[q * 2 + 0];
        float p1 = p * WD[q * 2 + 1];
        #pragma unroll
        for (int off = 16; off; off >>= 1) {
            p0 += __shfl_down(p0, off, 32);
            p1 += __shfl_down(p1, off, 32);
        }
        if (q == 0) {
            float l0 = p0 + BD[0], l1 = p1 + BD[1];
            float m = fmaxf(l0, l1);
            float e0 = expf(l0 - m), e1 = expf(l1 - m);
            float si = 1.0f / (e0 + e1);
            OUT[g * 2 + 0] = e0 * si;
            OUT[g * 2 + 1] = e1 * si;
        }
    }
}

extern "C" void kernel_launch(void* const* d_in, const int* in_sizes, int n_in,
                              void* d_out, int out_size, void* d_ws, size_t ws_size,
                              hipStream_t stream)
{
    const float* x    = (const float*)d_in[0];
    const float* ew   = (const float*)d_in[1];
    const int*   er   = (const int*)d_in[2];
    const int*   ec   = (const int*)d_in[3];
    const int*   seg  = (const int*)d_in[4];
    const float* w1_1 = (const float*)d_in[5];
    const float* w2_1 = (const float*)d_in[6];
    const float* b_1  = (const float*)d_in[7];
    const float* w1_2 = (const float*)d_in[8];
    const float* w2_2 = (const float*)d_in[9];
    const float* b_2  = (const float*)d_in[10];
    const float* w1_3 = (const float*)d_in[11];
    const float* w2_3 = (const float*)d_in[12];
    const float* b_3  = (const float*)d_in[13];
    const float* wd   = (const float*)d_in[14];
    const float* bd   = (const float*)d_in[15];

    float* ws = (float*)d_ws;
    int*   IW = (int*)d_ws;
    // Fully disjoint workspace — no aliasing hazards.
    __half* XPh    = (__half*)ws;                   // N x 32 fp16
    __half* CIa    = (__half*)(ws + 800000);        // N x 32 fp16
    unsigned int* tmp_sd = (unsigned int*)(ws + 1600000);  // E x 4B
    __half* tmp_w  = (__half*)(ws + 2400000);       // E x 2B
    __half* H2h    = (__half*)(ws + 3200000);       // N x 64 fp16
    __half* A2h    = (__half*)(ws + 4800000);       // N x 64 fp16
    __half* H3h    = (__half*)(ws + 6400000);       // N x 32 fp16
    __half* B2h    = (__half*)(ws + 7200000);       // N x 32 fp16
    unsigned int* packed = (unsigned int*)(IW + 8000000);  // E x 4B
    int*    rowptr = IW + 9000000;                  // N+1
    int*    ghist  = IW + 9060000;                  // NCB*256
    int*    bsum   = IW + 9115000;                  // NCB
    int*    start  = IW + 9120000;                  // G+1
    float*  WP     = ws + 9125000;                  // 64 x 128 packed layer-1 W

    dim3 blk(256);

    // ---- CSR build + prep (4 dispatches; bsort fuses layer-1 aggx) ----
    hist_prep<<<dim3(256 + 6478), blk, 0, stream>>>(er, x, seg, w1_1, w2_1,
                                                    ghist, XPh, start, WP);
    scan1<<<dim3(NCB), blk, 0, stream>>>(ghist, bsum);
    c_scatter<<<dim3(256), blk, 0, stream>>>(er, ec, ew, ghist, bsum, tmp_sd, tmp_w);
    bsort_aggx<<<dim3(NCB), dim3(512), 0, stream>>>(tmp_sd, tmp_w, bsum, XPh,
                                                    packed, rowptr, CIa);

    // Layers 1+2 fused dense: [CIa|XPh] @ WP + b1 -> relu -> @[W1_2|W2_2]
    dense12_kernel<<<dim3(MBLK), dim3(512), 0, stream>>>(CIa, XPh, WP, b_1,
                                                         w1_2, w2_2, b_2, H2h, A2h);
    spmm_h<64><<<dim3((N_NODES + 31) / 32), blk, 0, stream>>>(H2h, rowptr, packed, A2h);
    // Layer 3: relu(h2h)(64) -> 32; both outputs fp16
    dense3_kernel<<<dim3(MBLK), blk, 0, stream>>>(A2h, w1_3, w2_3, b_3, H3h, B2h);
    spmm_h<32><<<dim3(MBLK), blk, 0, stream>>>(H3h, rowptr, packed, B2h);

    // Pool + head (fused, atomic-free)
    pool_kernel<<<dim3(N_GRAPHS), blk, 0, stream>>>(B2h, start, wd, bd, (float*)d_out);
}